// Round 6
// baseline (536.322 us; speedup 1.0000x reference)
//
#include <hip/hip_runtime.h>
#include <hip/hip_fp16.h>

// GATv2 x3 + FC on MI355X. N=50000, E=800000(+N self loops), F=128, H=4, C=32.
// R5: gemm2 overhaul — register prefetch of next K-tile (hides global latency
//     that was serial-exposed 4x per block), split-column B mapping
//     (cols {q*4, q*4+64}: B-read banks 4k%32 = 2-way free, was 4-way).
constexpr int FDIM = 128;   // H*C
constexpr float SLOPE = 0.2f;

__device__ __forceinline__ float lrelu(float x) {
  return x > 0.f ? x : x * SLOPE;
}

struct F8 { float4 a, b; };
__device__ __forceinline__ F8 cvt8(uint4 u) {
  union { uint4 u; __half2 h[4]; } t;
  t.u = u;
  float2 f0 = __half22float2(t.h[0]);
  float2 f1 = __half22float2(t.h[1]);
  float2 f2 = __half22float2(t.h[2]);
  float2 f3 = __half22float2(t.h[3]);
  F8 r;
  r.a = make_float4(f0.x, f0.y, f1.x, f1.y);
  r.b = make_float4(f2.x, f2.y, f3.x, f3.y);
  return r;
}

// ---------------- SGEMM: out = hin @ W for W in {Wl, Wr}, fp16 out -------
// BM=128, BN=128, BK=32, 256 threads, 8x8 tile on cols {tc4, tc4+64}.
// Double-clocked: prefetch next K-tile to regs while computing current.
__global__ __launch_bounds__(256) void gemm2(
    const float* __restrict__ hin, const float* __restrict__ Wl,
    const float* __restrict__ Wr, __half* __restrict__ xl,
    __half* __restrict__ xr, int n) {
  const float* __restrict__ W = (blockIdx.y == 0) ? Wl : Wr;
  __half* __restrict__ out = (blockIdx.y == 0) ? xl : xr;
  __shared__ __align__(16) float At[32][132];  // k-major A: At[k][row]
  __shared__ __align__(16) float Bs[32][132];
  const int tid = threadIdx.x;
  const int row0 = blockIdx.x * 128;
  const int tr = (tid >> 4) * 8;       // 8 output rows
  const int tc4 = (tid & 15) * 4;      // cols tc4..tc4+3 and tc4+64..+67
  const int ar = tid >> 1, ac = (tid & 1) * 16;  // A stage: row ar, 16 k's
  const int gr = row0 + ar;
  const int brr = tid >> 3, bcc = (tid & 7) * 16; // B stage: row brr, 16 cols
  float acc[8][8];
#pragma unroll
  for (int i = 0; i < 8; ++i)
#pragma unroll
    for (int j = 0; j < 8; ++j) acc[i][j] = 0.f;

  const float4 f40 = make_float4(0.f, 0.f, 0.f, 0.f);
  float4 pa[4], pb[4];
#pragma unroll
  for (int u = 0; u < 4; ++u) {  // prefetch tile k0=0
    pa[u] = (gr < n) ? *(const float4*)(hin + (size_t)gr * FDIM + ac + 4 * u) : f40;
    pb[u] = *(const float4*)(W + (size_t)brr * FDIM + bcc + 4 * u);
  }

  for (int k0 = 0; k0 < 128; k0 += 32) {
    if (k0) __syncthreads();  // prior compute done before LDS overwrite
#pragma unroll
    for (int u = 0; u < 4; ++u) {
      At[ac + 4 * u + 0][ar] = pa[u].x;
      At[ac + 4 * u + 1][ar] = pa[u].y;
      At[ac + 4 * u + 2][ar] = pa[u].z;
      At[ac + 4 * u + 3][ar] = pa[u].w;
      *(float4*)&Bs[brr][bcc + 4 * u] = pb[u];
    }
    __syncthreads();
    if (k0 + 32 < 128) {  // issue next tile's loads; hidden under compute
#pragma unroll
      for (int u = 0; u < 4; ++u) {
        pa[u] = (gr < n)
            ? *(const float4*)(hin + (size_t)gr * FDIM + k0 + 32 + ac + 4 * u)
            : f40;
        pb[u] = *(const float4*)(W + (size_t)(k0 + 32 + brr) * FDIM + bcc + 4 * u);
      }
    }
#pragma unroll
    for (int kk = 0; kk < 32; ++kk) {
      float4 a0 = *(const float4*)&At[kk][tr];
      float4 a1 = *(const float4*)&At[kk][tr + 4];
      float4 b0 = *(const float4*)&Bs[kk][tc4];
      float4 b1 = *(const float4*)&Bs[kk][tc4 + 64];
      float av[8] = {a0.x, a0.y, a0.z, a0.w, a1.x, a1.y, a1.z, a1.w};
      float bv[8] = {b0.x, b0.y, b0.z, b0.w, b1.x, b1.y, b1.z, b1.w};
#pragma unroll
      for (int i = 0; i < 8; ++i)
#pragma unroll
        for (int j = 0; j < 8; ++j)
          acc[i][j] = fmaf(av[i], bv[j], acc[i][j]);
    }
  }
#pragma unroll
  for (int i = 0; i < 8; ++i) {
    int orow = row0 + tr + i;
    if (orow < n) {
      union { uint2 u; __half2 h[2]; } p0, p1;
      p0.h[0] = __floats2half2_rn(acc[i][0], acc[i][1]);
      p0.h[1] = __floats2half2_rn(acc[i][2], acc[i][3]);
      p1.h[0] = __floats2half2_rn(acc[i][4], acc[i][5]);
      p1.h[1] = __floats2half2_rn(acc[i][6], acc[i][7]);
      *(uint2*)(out + (size_t)orow * FDIM + tc4) = p0.u;
      *(uint2*)(out + (size_t)orow * FDIM + tc4 + 64) = p1.u;
    }
  }
}

// ---------------- CSR build: histogram -> hierarchical scan -> scatter ---
__global__ __launch_bounds__(256) void hist_dst(const int* __restrict__ dstI,
                                                int* __restrict__ deg, int e_cnt) {
  int i = blockIdx.x * blockDim.x + threadIdx.x;
  int stride = gridDim.x * blockDim.x;
  for (; i < e_cnt; i += stride) atomicAdd(&deg[dstI[i]], 1);
}

__global__ __launch_bounds__(1024) void scan_local(
    const int* __restrict__ deg, int* __restrict__ rowptr,
    int* __restrict__ btot, int n) {
  __shared__ int lds[1024];
  const int t = threadIdx.x;
  const int i = blockIdx.x * 1024 + t;
  int v = (i < n) ? deg[i] : 0;
  lds[t] = v;
  __syncthreads();
  for (int off = 1; off < 1024; off <<= 1) {
    int u = (t >= off) ? lds[t - off] : 0;
    __syncthreads();
    lds[t] += u;
    __syncthreads();
  }
  if (i < n) rowptr[i] = lds[t] - v;  // exclusive within block
  if (t == 1023) btot[blockIdx.x] = lds[1023];
}

__global__ __launch_bounds__(1024) void scan_btot(int* __restrict__ btot, int nb) {
  __shared__ int lds[1024];
  const int t = threadIdx.x;
  int v = (t < nb) ? btot[t] : 0;
  lds[t] = v;
  __syncthreads();
  for (int off = 1; off < 1024; off <<= 1) {
    int u = (t >= off) ? lds[t - off] : 0;
    __syncthreads();
    lds[t] += u;
    __syncthreads();
  }
  if (t < nb) btot[t] = lds[t] - v;
}

__global__ __launch_bounds__(1024) void scan_add(
    int* __restrict__ rowptr, int* __restrict__ rowcur,
    const int* __restrict__ btot, int n, int e_cnt) {
  const int i = blockIdx.x * 1024 + threadIdx.x;
  if (i < n) {
    int v = rowptr[i] + btot[blockIdx.x];
    rowptr[i] = v;
    rowcur[i] = v;
  }
  if (i == 0) rowptr[n] = e_cnt;
}

__global__ __launch_bounds__(256) void scatter_csr(
    const int* __restrict__ srcI, const int* __restrict__ dstI,
    int* __restrict__ rowcur, int* __restrict__ csr, int e_cnt) {
  int i = blockIdx.x * blockDim.x + threadIdx.x;
  int stride = gridDim.x * blockDim.x;
  for (; i < e_cnt; i += stride) {
    int pos = atomicAdd(&rowcur[dstI[i]], 1);
    csr[pos] = srcI[i];
  }
}

// ------- fused per-node GATv2: 4 edges per wave, fp16 gathers ------------
// lane = g*16 + q; group g handles edges rs+4t+g; lane q covers features
// q*8..q*8+7 (head = q>>2). Self-loop seeds group 0's state.
template <int LAST>
__global__ __launch_bounds__(256) void fused_attn(
    const __half* __restrict__ xl, const __half* __restrict__ xr,
    const int* __restrict__ rowptr, const int* __restrict__ csr,
    const float* __restrict__ att, const float* __restrict__ bias,
    const float* __restrict__ Wf, const float* __restrict__ bf,
    float* __restrict__ out, int n) {
  const int nid = (int)((blockIdx.x * (size_t)blockDim.x + threadIdx.x) >> 6);
  const int lane = threadIdx.x & 63;
  if (nid >= n) return;
  const int g = lane >> 4;
  const int q = lane & 15;
  const int f8 = q * 8;
  const float4 attA = *(const float4*)(att + f8);
  const float4 attB = *(const float4*)(att + f8 + 4);
  const F8 xrv = cvt8(*(const uint4*)(xr + (size_t)nid * FDIM + f8));
  const F8 xld = cvt8(*(const uint4*)(xl + (size_t)nid * FDIM + f8));
  const float4 xrA = xrv.a, xrB = xrv.b;
  const float4 xldA = xld.a, xldB = xld.b;

  // self-edge logit (reduce over the 4-lane head quad)
  float ps = fmaf(lrelu(xldA.x + xrA.x), attA.x,
             fmaf(lrelu(xldA.y + xrA.y), attA.y,
             fmaf(lrelu(xldA.z + xrA.z), attA.z,
             fmaf(lrelu(xldA.w + xrA.w), attA.w,
             fmaf(lrelu(xldB.x + xrB.x), attB.x,
             fmaf(lrelu(xldB.y + xrB.y), attB.y,
             fmaf(lrelu(xldB.z + xrB.z), attB.z,
                  lrelu(xldB.w + xrB.w) * attB.w)))))));
  ps += __shfl_xor(ps, 1);
  ps += __shfl_xor(ps, 2);

  float m = (g == 0) ? ps : -1e30f;
  float s = (g == 0) ? 1.f : 0.f;
  float4 accA = (g == 0) ? xldA : make_float4(0.f, 0.f, 0.f, 0.f);
  float4 accB = (g == 0) ? xldB : make_float4(0.f, 0.f, 0.f, 0.f);

  const int rs = rowptr[nid], re = rowptr[nid + 1];
  int jj = rs + g;
  bool v = jj < re;
  int sidx = v ? csr[jj] : 0;
  uint4 cur = make_uint4(0u, 0u, 0u, 0u);
  if (v) cur = *(const uint4*)(xl + (size_t)sidx * FDIM + f8);

  for (int t = rs; t < re; t += 4) {
    int jn = t + 4 + g;
    bool vn = jn < re;
    int sn = vn ? csr[jn] : 0;
    uint4 nxt = make_uint4(0u, 0u, 0u, 0u);
    if (vn) nxt = *(const uint4*)(xl + (size_t)sn * FDIM + f8);
    F8 xa = cvt8(cur);
    float4 xaA = xa.a, xaB = xa.b;
    float p = fmaf(lrelu(xaA.x + xrA.x), attA.x,
              fmaf(lrelu(xaA.y + xrA.y), attA.y,
              fmaf(lrelu(xaA.z + xrA.z), attA.z,
              fmaf(lrelu(xaA.w + xrA.w), attA.w,
              fmaf(lrelu(xaB.x + xrB.x), attB.x,
              fmaf(lrelu(xaB.y + xrB.y), attB.y,
              fmaf(lrelu(xaB.z + xrB.z), attB.z,
                   lrelu(xaB.w + xrB.w) * attB.w)))))));
    p += __shfl_xor(p, 1);
    p += __shfl_xor(p, 2);
    if (v) {
      float mn = fmaxf(m, p);
      float sc = __expf(m - mn);
      float w = __expf(p - mn);
      s = fmaf(s, sc, w);
      accA.x = fmaf(accA.x, sc, w * xaA.x);
      accA.y = fmaf(accA.y, sc, w * xaA.y);
      accA.z = fmaf(accA.z, sc, w * xaA.z);
      accA.w = fmaf(accA.w, sc, w * xaA.w);
      accB.x = fmaf(accB.x, sc, w * xaB.x);
      accB.y = fmaf(accB.y, sc, w * xaB.y);
      accB.z = fmaf(accB.z, sc, w * xaB.z);
      accB.w = fmaf(accB.w, sc, w * xaB.w);
      m = mn;
    }
    v = vn; cur = nxt;
  }

  // merge the 4 groups' online-softmax states (xor 16, then xor 32)
#pragma unroll
  for (int off = 16; off <= 32; off <<= 1) {
    float mo = __shfl_xor(m, off);
    float so = __shfl_xor(s, off);
    float4 aoA, aoB;
    aoA.x = __shfl_xor(accA.x, off); aoA.y = __shfl_xor(accA.y, off);
    aoA.z = __shfl_xor(accA.z, off); aoA.w = __shfl_xor(accA.w, off);
    aoB.x = __shfl_xor(accB.x, off); aoB.y = __shfl_xor(accB.y, off);
    aoB.z = __shfl_xor(accB.z, off); aoB.w = __shfl_xor(accB.w, off);
    float M = fmaxf(m, mo);
    float e0 = __expf(m - M), e1 = __expf(mo - M);
    s = fmaf(s, e0, so * e1);
    accA.x = fmaf(accA.x, e0, aoA.x * e1);
    accA.y = fmaf(accA.y, e0, aoA.y * e1);
    accA.z = fmaf(accA.z, e0, aoA.z * e1);
    accA.w = fmaf(accA.w, e0, aoA.w * e1);
    accB.x = fmaf(accB.x, e0, aoB.x * e1);
    accB.y = fmaf(accB.y, e0, aoB.y * e1);
    accB.z = fmaf(accB.z, e0, aoB.z * e1);
    accB.w = fmaf(accB.w, e0, aoB.w * e1);
    m = M;
  }

  const float inv = 1.f / s;
  const float4 bA = *(const float4*)(bias + f8);
  const float4 bB = *(const float4*)(bias + f8 + 4);
  float o0 = fmaxf(fmaf(accA.x, inv, bA.x), 0.f);
  float o1 = fmaxf(fmaf(accA.y, inv, bA.y), 0.f);
  float o2 = fmaxf(fmaf(accA.z, inv, bA.z), 0.f);
  float o3 = fmaxf(fmaf(accA.w, inv, bA.w), 0.f);
  float o4 = fmaxf(fmaf(accB.x, inv, bB.x), 0.f);
  float o5 = fmaxf(fmaf(accB.y, inv, bB.y), 0.f);
  float o6 = fmaxf(fmaf(accB.z, inv, bB.z), 0.f);
  float o7 = fmaxf(fmaf(accB.w, inv, bB.w), 0.f);

  if (LAST == 0) {
    if (g == 0) {
      *(float4*)(out + (size_t)nid * FDIM + f8) = make_float4(o0, o1, o2, o3);
      *(float4*)(out + (size_t)nid * FDIM + f8 + 4) = make_float4(o4, o5, o6, o7);
    }
  } else {
    const float4 wA = *(const float4*)(Wf + f8);
    const float4 wB = *(const float4*)(Wf + f8 + 4);
    float y = fmaf(o0, wA.x, fmaf(o1, wA.y, fmaf(o2, wA.z,
              fmaf(o3, wA.w, fmaf(o4, wB.x, fmaf(o5, wB.y,
              fmaf(o6, wB.z, o7 * wB.w)))))));
    y += __shfl_xor(y, 1);
    y += __shfl_xor(y, 2);
    y += __shfl_xor(y, 4);
    y += __shfl_xor(y, 8);
    if (lane == 0) out[nid] = y + bf[0];
  }
}

extern "C" void kernel_launch(void* const* d_in, const int* in_sizes, int n_in,
                              void* d_out, int out_size, void* d_ws, size_t ws_size,
                              hipStream_t stream) {
  const float* x = (const float*)d_in[0];
  const int* ei = (const int*)d_in[1];
  const int n = in_sizes[0] / FDIM;
  const int e_cnt = in_sizes[1] / 2;
  const int* srcI = ei;
  const int* dstI = ei + e_cnt;

  const float* Wl[3]  = {(const float*)d_in[2], (const float*)d_in[6], (const float*)d_in[10]};
  const float* Wr[3]  = {(const float*)d_in[3], (const float*)d_in[7], (const float*)d_in[11]};
  const float* att[3] = {(const float*)d_in[4], (const float*)d_in[8], (const float*)d_in[12]};
  const float* bs[3]  = {(const float*)d_in[5], (const float*)d_in[9], (const float*)d_in[13]};
  const float* Wf = (const float*)d_in[14];
  const float* bf = (const float*)d_in[15];

  __half* xlh = (__half*)d_ws;
  __half* xrh = xlh + (size_t)n * FDIM;
  float* hbuf = (float*)(xrh + (size_t)n * FDIM);
  int* deg    = (int*)(hbuf + (size_t)n * FDIM);
  int* rowptr = deg + n;
  int* rowcur = rowptr + n + 1;
  int* csr    = rowcur + n;
  int* btot   = csr + e_cnt;

  const int nb = (n + 1023) / 1024;

  // ---- CSR build (once per call; serves all 3 layers) ----
  hipMemsetAsync(deg, 0, (size_t)n * sizeof(int), stream);
  hist_dst<<<(e_cnt + 255) / 256, 256, 0, stream>>>(dstI, deg, e_cnt);
  scan_local<<<nb, 1024, 0, stream>>>(deg, rowptr, btot, n);
  scan_btot<<<1, 1024, 0, stream>>>(btot, nb);
  scan_add<<<nb, 1024, 0, stream>>>(rowptr, rowcur, btot, n, e_cnt);
  scatter_csr<<<(e_cnt + 255) / 256, 256, 0, stream>>>(srcI, dstI, rowcur, csr, e_cnt);

  const float* hin = x;
  const int gemmGridX = (n + 127) / 128;
  const int nodeBlocks = (n + 3) / 4;  // 4 waves (nodes) per block

  for (int L = 0; L < 3; ++L) {
    gemm2<<<dim3(gemmGridX, 2), 256, 0, stream>>>(hin, Wl[L], Wr[L], xlh, xrh, n);
    if (L < 2) {
      fused_attn<0><<<nodeBlocks, 256, 0, stream>>>(xlh, xrh, rowptr, csr, att[L],
                                                    bs[L], nullptr, nullptr, hbuf, n);
      hin = hbuf;
    } else {
      fused_attn<1><<<nodeBlocks, 256, 0, stream>>>(xlh, xrh, rowptr, csr, att[L],
                                                    bs[L], Wf, bf, (float*)d_out, n);
    }
  }
}

// Round 7
// 384.947 us; speedup vs baseline: 1.3932x; 1.3932x over previous
//
#include <hip/hip_runtime.h>
#include <hip/hip_fp16.h>

// GATv2 x3 + FC on MI355X. N=50000, E=800000(+N self loops), F=128, H=4, C=32.
// R6: GEMM moved to MFMA fp16 (fp32 accumulate). prep_w transposes all 6 W
//     to fp16 Wt[col][k] once; gemm_mfma computes xl AND xr per block
//     (shared A staging, 8 waves = 4 row-blocks x 2 outputs).
//     R5's reg-prefetch reverted (it spilled: +26MB scratch writes/dispatch).
constexpr int FDIM = 128;   // H*C
constexpr float SLOPE = 0.2f;

using half8 = __attribute__((ext_vector_type(8))) _Float16;
using f32x4 = __attribute__((ext_vector_type(4))) float;

__device__ __forceinline__ float lrelu(float x) {
  return x > 0.f ? x : x * SLOPE;
}

struct F8 { float4 a, b; };
__device__ __forceinline__ F8 cvt8(uint4 u) {
  union { uint4 u; __half2 h[4]; } t;
  t.u = u;
  float2 f0 = __half22float2(t.h[0]);
  float2 f1 = __half22float2(t.h[1]);
  float2 f2 = __half22float2(t.h[2]);
  float2 f3 = __half22float2(t.h[3]);
  F8 r;
  r.a = make_float4(f0.x, f0.y, f1.x, f1.y);
  r.b = make_float4(f2.x, f2.y, f3.x, f3.y);
  return r;
}

// ---- prep_w: W[k][c] fp32 -> Wt[c][k] fp16, 6 matrices (one per block) ---
__global__ __launch_bounds__(256) void prep_w(
    const float* __restrict__ W0, const float* __restrict__ W1,
    const float* __restrict__ W2, const float* __restrict__ W3,
    const float* __restrict__ W4, const float* __restrict__ W5,
    __half* __restrict__ Wt) {
  const float* Ws[6] = {W0, W1, W2, W3, W4, W5};
  const float* W = Ws[blockIdx.x];
  __half* o = Wt + (size_t)blockIdx.x * FDIM * FDIM;
  const int t = threadIdx.x;
  const int c4 = (t & 31) * 4;
#pragma unroll
  for (int rep = 0; rep < 16; ++rep) {
    int k = (t >> 5) + rep * 8;
    float4 v = *(const float4*)(W + (size_t)k * FDIM + c4);
    o[(size_t)(c4 + 0) * FDIM + k] = __float2half(v.x);
    o[(size_t)(c4 + 1) * FDIM + k] = __float2half(v.y);
    o[(size_t)(c4 + 2) * FDIM + k] = __float2half(v.z);
    o[(size_t)(c4 + 3) * FDIM + k] = __float2half(v.w);
  }
}

// ---- gemm_mfma: xl = hin@Wl, xr = hin@Wr (fp16 out, fp32 accumulate) ----
// 512 threads = 8 waves: wave w -> output sel=w>>2 (xl/xr), row-block w&3.
// K-stepped (BK=32) LDS staging, padded stride 40 halves (80B, 2-way banks).
__global__ __launch_bounds__(512, 4) void gemm_mfma(
    const float* __restrict__ hin, const __half* __restrict__ Wlt,
    const __half* __restrict__ Wrt, __half* __restrict__ xl,
    __half* __restrict__ xr, int n) {
  __shared__ __half Ah[128][40];
  __shared__ __half Bsl[2][128][40];
  const int tid = threadIdx.x;
  const int row0 = blockIdx.x * 128;
  const int wv = tid >> 6;
  const int lane = tid & 63;
  const int sel = wv >> 2;       // 0: xl, 1: xr
  const int rb = wv & 3;         // 32-row block within tile
  const int l15 = lane & 15;
  const int l4 = lane >> 4;      // 0..3

  f32x4 acc[2][8];
#pragma unroll
  for (int i = 0; i < 2; ++i)
#pragma unroll
    for (int j = 0; j < 8; ++j) acc[i][j] = (f32x4){0.f, 0.f, 0.f, 0.f};

  // staging assignments
  const int sr = tid >> 2;            // A row 0..127
  const int sc = (tid & 3) * 8;       // A k-chunk 0/8/16/24
  const int bslab = tid >> 8;         // 0: Wl, 1: Wr
  const int bidx = tid & 255;
  const int bc = bidx >> 1;           // col 0..127
  const int bko = (bidx & 1) * 16;    // k offset 0/16
  const __half* Wsrc = bslab ? Wrt : Wlt;
  const int gr = row0 + sr;

  for (int k0 = 0; k0 < 128; k0 += 32) {
    if (k0) __syncthreads();
    {  // stage A rows row0+sr, k = k0+sc..+7 (fp32 -> fp16)
      float4 v0 = make_float4(0.f, 0.f, 0.f, 0.f), v1 = v0;
      if (gr < n) {
        v0 = *(const float4*)(hin + (size_t)gr * FDIM + k0 + sc);
        v1 = *(const float4*)(hin + (size_t)gr * FDIM + k0 + sc + 4);
      }
      __half* dst = &Ah[sr][sc];
      dst[0] = __float2half(v0.x); dst[1] = __float2half(v0.y);
      dst[2] = __float2half(v0.z); dst[3] = __float2half(v0.w);
      dst[4] = __float2half(v1.x); dst[5] = __float2half(v1.y);
      dst[6] = __float2half(v1.z); dst[7] = __float2half(v1.w);
    }
    {  // stage B slab: Wt[col][k0+bko .. +16] (already fp16)
      const uint4* src = (const uint4*)(Wsrc + (size_t)bc * FDIM + k0 + bko);
      uint4 w0 = src[0], w1 = src[1];
      *(uint4*)&Bsl[bslab][bc][bko] = w0;
      *(uint4*)&Bsl[bslab][bc][bko + 8] = w1;
    }
    __syncthreads();
    // compute: 2 A-frags x 8 B-frags -> 16 MFMA per wave per K-step
    half8 a0 = *(const half8*)&Ah[rb * 32 + l15][l4 * 8];
    half8 a1 = *(const half8*)&Ah[rb * 32 + 16 + l15][l4 * 8];
#pragma unroll
    for (int nf = 0; nf < 8; ++nf) {
      half8 b = *(const half8*)&Bsl[sel][nf * 16 + l15][l4 * 8];
      acc[0][nf] = __builtin_amdgcn_mfma_f32_16x16x32_f16(a0, b, acc[0][nf], 0, 0, 0);
      acc[1][nf] = __builtin_amdgcn_mfma_f32_16x16x32_f16(a1, b, acc[1][nf], 0, 0, 0);
    }
  }

  // epilogue: D[row=af*16+l4*4+r][col=nf*16+l15] -> fp16 store
  __half* out = sel ? xr : xl;
#pragma unroll
  for (int af = 0; af < 2; ++af) {
#pragma unroll
    for (int nf = 0; nf < 8; ++nf) {
      int col = nf * 16 + l15;
#pragma unroll
      for (int r = 0; r < 4; ++r) {
        int row = row0 + rb * 32 + af * 16 + l4 * 4 + r;
        if (row < n) out[(size_t)row * FDIM + col] = __float2half(acc[af][nf][r]);
      }
    }
  }
}

// ---------------- CSR build: histogram -> hierarchical scan -> scatter ---
__global__ __launch_bounds__(256) void hist_dst(const int* __restrict__ dstI,
                                                int* __restrict__ deg, int e_cnt) {
  int i = blockIdx.x * blockDim.x + threadIdx.x;
  int stride = gridDim.x * blockDim.x;
  for (; i < e_cnt; i += stride) atomicAdd(&deg[dstI[i]], 1);
}

__global__ __launch_bounds__(1024) void scan_local(
    const int* __restrict__ deg, int* __restrict__ rowptr,
    int* __restrict__ btot, int n) {
  __shared__ int lds[1024];
  const int t = threadIdx.x;
  const int i = blockIdx.x * 1024 + t;
  int v = (i < n) ? deg[i] : 0;
  lds[t] = v;
  __syncthreads();
  for (int off = 1; off < 1024; off <<= 1) {
    int u = (t >= off) ? lds[t - off] : 0;
    __syncthreads();
    lds[t] += u;
    __syncthreads();
  }
  if (i < n) rowptr[i] = lds[t] - v;  // exclusive within block
  if (t == 1023) btot[blockIdx.x] = lds[1023];
}

__global__ __launch_bounds__(1024) void scan_btot(int* __restrict__ btot, int nb) {
  __shared__ int lds[1024];
  const int t = threadIdx.x;
  int v = (t < nb) ? btot[t] : 0;
  lds[t] = v;
  __syncthreads();
  for (int off = 1; off < 1024; off <<= 1) {
    int u = (t >= off) ? lds[t - off] : 0;
    __syncthreads();
    lds[t] += u;
    __syncthreads();
  }
  if (t < nb) btot[t] = lds[t] - v;
}

__global__ __launch_bounds__(1024) void scan_add(
    int* __restrict__ rowptr, int* __restrict__ rowcur,
    const int* __restrict__ btot, int n, int e_cnt) {
  const int i = blockIdx.x * 1024 + threadIdx.x;
  if (i < n) {
    int v = rowptr[i] + btot[blockIdx.x];
    rowptr[i] = v;
    rowcur[i] = v;
  }
  if (i == 0) rowptr[n] = e_cnt;
}

__global__ __launch_bounds__(256) void scatter_csr(
    const int* __restrict__ srcI, const int* __restrict__ dstI,
    int* __restrict__ rowcur, int* __restrict__ csr, int e_cnt) {
  int i = blockIdx.x * blockDim.x + threadIdx.x;
  int stride = gridDim.x * blockDim.x;
  for (; i < e_cnt; i += stride) {
    int pos = atomicAdd(&rowcur[dstI[i]], 1);
    csr[pos] = srcI[i];
  }
}

// ------- fused per-node GATv2: 4 edges per wave, fp16 gathers ------------
template <int LAST>
__global__ __launch_bounds__(256) void fused_attn(
    const __half* __restrict__ xl, const __half* __restrict__ xr,
    const int* __restrict__ rowptr, const int* __restrict__ csr,
    const float* __restrict__ att, const float* __restrict__ bias,
    const float* __restrict__ Wf, const float* __restrict__ bf,
    float* __restrict__ out, int n) {
  const int nid = (int)((blockIdx.x * (size_t)blockDim.x + threadIdx.x) >> 6);
  const int lane = threadIdx.x & 63;
  if (nid >= n) return;
  const int g = lane >> 4;
  const int q = lane & 15;
  const int f8 = q * 8;
  const float4 attA = *(const float4*)(att + f8);
  const float4 attB = *(const float4*)(att + f8 + 4);
  const F8 xrv = cvt8(*(const uint4*)(xr + (size_t)nid * FDIM + f8));
  const F8 xld = cvt8(*(const uint4*)(xl + (size_t)nid * FDIM + f8));
  const float4 xrA = xrv.a, xrB = xrv.b;
  const float4 xldA = xld.a, xldB = xld.b;

  float ps = fmaf(lrelu(xldA.x + xrA.x), attA.x,
             fmaf(lrelu(xldA.y + xrA.y), attA.y,
             fmaf(lrelu(xldA.z + xrA.z), attA.z,
             fmaf(lrelu(xldA.w + xrA.w), attA.w,
             fmaf(lrelu(xldB.x + xrB.x), attB.x,
             fmaf(lrelu(xldB.y + xrB.y), attB.y,
             fmaf(lrelu(xldB.z + xrB.z), attB.z,
                  lrelu(xldB.w + xrB.w) * attB.w)))))));
  ps += __shfl_xor(ps, 1);
  ps += __shfl_xor(ps, 2);

  float m = (g == 0) ? ps : -1e30f;
  float s = (g == 0) ? 1.f : 0.f;
  float4 accA = (g == 0) ? xldA : make_float4(0.f, 0.f, 0.f, 0.f);
  float4 accB = (g == 0) ? xldB : make_float4(0.f, 0.f, 0.f, 0.f);

  const int rs = rowptr[nid], re = rowptr[nid + 1];
  int jj = rs + g;
  bool v = jj < re;
  int sidx = v ? csr[jj] : 0;
  uint4 cur = make_uint4(0u, 0u, 0u, 0u);
  if (v) cur = *(const uint4*)(xl + (size_t)sidx * FDIM + f8);

  for (int t = rs; t < re; t += 4) {
    int jn = t + 4 + g;
    bool vn = jn < re;
    int sn = vn ? csr[jn] : 0;
    uint4 nxt = make_uint4(0u, 0u, 0u, 0u);
    if (vn) nxt = *(const uint4*)(xl + (size_t)sn * FDIM + f8);
    F8 xa = cvt8(cur);
    float4 xaA = xa.a, xaB = xa.b;
    float p = fmaf(lrelu(xaA.x + xrA.x), attA.x,
              fmaf(lrelu(xaA.y + xrA.y), attA.y,
              fmaf(lrelu(xaA.z + xrA.z), attA.z,
              fmaf(lrelu(xaA.w + xrA.w), attA.w,
              fmaf(lrelu(xaB.x + xrB.x), attB.x,
              fmaf(lrelu(xaB.y + xrB.y), attB.y,
              fmaf(lrelu(xaB.z + xrB.z), attB.z,
                   lrelu(xaB.w + xrB.w) * attB.w)))))));
    p += __shfl_xor(p, 1);
    p += __shfl_xor(p, 2);
    if (v) {
      float mn = fmaxf(m, p);
      float sc = __expf(m - mn);
      float w = __expf(p - mn);
      s = fmaf(s, sc, w);
      accA.x = fmaf(accA.x, sc, w * xaA.x);
      accA.y = fmaf(accA.y, sc, w * xaA.y);
      accA.z = fmaf(accA.z, sc, w * xaA.z);
      accA.w = fmaf(accA.w, sc, w * xaA.w);
      accB.x = fmaf(accB.x, sc, w * xaB.x);
      accB.y = fmaf(accB.y, sc, w * xaB.y);
      accB.z = fmaf(accB.z, sc, w * xaB.z);
      accB.w = fmaf(accB.w, sc, w * xaB.w);
      m = mn;
    }
    v = vn; cur = nxt;
  }

#pragma unroll
  for (int off = 16; off <= 32; off <<= 1) {
    float mo = __shfl_xor(m, off);
    float so = __shfl_xor(s, off);
    float4 aoA, aoB;
    aoA.x = __shfl_xor(accA.x, off); aoA.y = __shfl_xor(accA.y, off);
    aoA.z = __shfl_xor(accA.z, off); aoA.w = __shfl_xor(accA.w, off);
    aoB.x = __shfl_xor(accB.x, off); aoB.y = __shfl_xor(accB.y, off);
    aoB.z = __shfl_xor(accB.z, off); aoB.w = __shfl_xor(accB.w, off);
    float M = fmaxf(m, mo);
    float e0 = __expf(m - M), e1 = __expf(mo - M);
    s = fmaf(s, e0, so * e1);
    accA.x = fmaf(accA.x, e0, aoA.x * e1);
    accA.y = fmaf(accA.y, e0, aoA.y * e1);
    accA.z = fmaf(accA.z, e0, aoA.z * e1);
    accA.w = fmaf(accA.w, e0, aoA.w * e1);
    accB.x = fmaf(accB.x, e0, aoB.x * e1);
    accB.y = fmaf(accB.y, e0, aoB.y * e1);
    accB.z = fmaf(accB.z, e0, aoB.z * e1);
    accB.w = fmaf(accB.w, e0, aoB.w * e1);
    m = M;
  }

  const float inv = 1.f / s;
  const float4 bA = *(const float4*)(bias + f8);
  const float4 bB = *(const float4*)(bias + f8 + 4);
  float o0 = fmaxf(fmaf(accA.x, inv, bA.x), 0.f);
  float o1 = fmaxf(fmaf(accA.y, inv, bA.y), 0.f);
  float o2 = fmaxf(fmaf(accA.z, inv, bA.z), 0.f);
  float o3 = fmaxf(fmaf(accA.w, inv, bA.w), 0.f);
  float o4 = fmaxf(fmaf(accB.x, inv, bB.x), 0.f);
  float o5 = fmaxf(fmaf(accB.y, inv, bB.y), 0.f);
  float o6 = fmaxf(fmaf(accB.z, inv, bB.z), 0.f);
  float o7 = fmaxf(fmaf(accB.w, inv, bB.w), 0.f);

  if (LAST == 0) {
    if (g == 0) {
      *(float4*)(out + (size_t)nid * FDIM + f8) = make_float4(o0, o1, o2, o3);
      *(float4*)(out + (size_t)nid * FDIM + f8 + 4) = make_float4(o4, o5, o6, o7);
    }
  } else {
    const float4 wA = *(const float4*)(Wf + f8);
    const float4 wB = *(const float4*)(Wf + f8 + 4);
    float y = fmaf(o0, wA.x, fmaf(o1, wA.y, fmaf(o2, wA.z,
              fmaf(o3, wA.w, fmaf(o4, wB.x, fmaf(o5, wB.y,
              fmaf(o6, wB.z, o7 * wB.w)))))));
    y += __shfl_xor(y, 1);
    y += __shfl_xor(y, 2);
    y += __shfl_xor(y, 4);
    y += __shfl_xor(y, 8);
    if (lane == 0) out[nid] = y + bf[0];
  }
}

extern "C" void kernel_launch(void* const* d_in, const int* in_sizes, int n_in,
                              void* d_out, int out_size, void* d_ws, size_t ws_size,
                              hipStream_t stream) {
  const float* x = (const float*)d_in[0];
  const int* ei = (const int*)d_in[1];
  const int n = in_sizes[0] / FDIM;
  const int e_cnt = in_sizes[1] / 2;
  const int* srcI = ei;
  const int* dstI = ei + e_cnt;

  const float* Wl[3]  = {(const float*)d_in[2], (const float*)d_in[6], (const float*)d_in[10]};
  const float* Wr[3]  = {(const float*)d_in[3], (const float*)d_in[7], (const float*)d_in[11]};
  const float* att[3] = {(const float*)d_in[4], (const float*)d_in[8], (const float*)d_in[12]};
  const float* bs[3]  = {(const float*)d_in[5], (const float*)d_in[9], (const float*)d_in[13]};
  const float* Wf = (const float*)d_in[14];
  const float* bf = (const float*)d_in[15];

  __half* xlh = (__half*)d_ws;
  __half* xrh = xlh + (size_t)n * FDIM;
  float* hbuf = (float*)(xrh + (size_t)n * FDIM);
  int* deg    = (int*)(hbuf + (size_t)n * FDIM);
  int* rowptr = deg + n;
  int* rowcur = rowptr + n + 1;
  int* csr    = rowcur + n;
  int* btot   = csr + e_cnt;
  __half* Wt  = (__half*)(btot + 1024);   // 6 x 128 x 128 fp16 = 192 KiB

  const int nb = (n + 1023) / 1024;

  // ---- weight transpose/convert + CSR build (serve all 3 layers) ----
  prep_w<<<6, 256, 0, stream>>>(Wl[0], Wr[0], Wl[1], Wr[1], Wl[2], Wr[2], Wt);
  hipMemsetAsync(deg, 0, (size_t)n * sizeof(int), stream);
  hist_dst<<<(e_cnt + 255) / 256, 256, 0, stream>>>(dstI, deg, e_cnt);
  scan_local<<<nb, 1024, 0, stream>>>(deg, rowptr, btot, n);
  scan_btot<<<1, 1024, 0, stream>>>(btot, nb);
  scan_add<<<nb, 1024, 0, stream>>>(rowptr, rowcur, btot, n, e_cnt);
  scatter_csr<<<(e_cnt + 255) / 256, 256, 0, stream>>>(srcI, dstI, rowcur, csr, e_cnt);

  const float* hin = x;
  const int gemmGrid = (n + 127) / 128;
  const int nodeBlocks = (n + 3) / 4;  // 4 waves (nodes) per block

  for (int L = 0; L < 3; ++L) {
    const __half* Wlt = Wt + (size_t)(2 * L) * FDIM * FDIM;
    const __half* Wrt = Wt + (size_t)(2 * L + 1) * FDIM * FDIM;
    gemm_mfma<<<gemmGrid, 512, 0, stream>>>(hin, Wlt, Wrt, xlh, xrh, n);
    if (L < 2) {
      fused_attn<0><<<nodeBlocks, 256, 0, stream>>>(xlh, xrh, rowptr, csr, att[L],
                                                    bs[L], nullptr, nullptr, hbuf, n);
      hin = hbuf;
    } else {
      fused_attn<1><<<nodeBlocks, 256, 0, stream>>>(xlh, xrh, rowptr, csr, att[L],
                                                    bs[L], Wf, bf, (float*)d_out, n);
    }
  }
}

// Round 9
// 379.789 us; speedup vs baseline: 1.4122x; 1.0136x over previous
//
#include <hip/hip_runtime.h>
#include <hip/hip_fp16.h>

// GATv2 x3 + FC on MI355X. N=50000, E=800000(+N self loops), F=128, H=4, C=32.
// R8 = R7 with compile fix: ROCm 7.2 lacks __hmax2 -> packed fp16 ops done on
//     _Float16 ext-vectors (lower to v_pk_max/add/mul_f16).
//     (a) fused_attn packed-fp16 logits + 2-deep edge prefetch;
//     (b) hbuf stored fp16; (c) gemm A-staging one ds_write_b128.
constexpr int FDIM = 128;   // H*C
constexpr float SLOPE = 0.2f;

using half8 = __attribute__((ext_vector_type(8))) _Float16;
using f32x4 = __attribute__((ext_vector_type(4))) float;
using h2v   = __attribute__((ext_vector_type(2))) _Float16;

union H2U { __half2 s; h2v v; unsigned int u; };

__device__ __forceinline__ float fdot2f(h2v a, h2v b, float c) {
  return __builtin_amdgcn_fdot2(a, b, c, false);
}

union U4 { uint4 u; __half2 h[4]; };

// logit partial for 8 features held as 4 half2: sum att*lrelu(xa+xr)
__device__ __forceinline__ float edge_logit(const __half2* xa2, const __half2* xr2,
                                            const h2v* att2, h2v c02) {
  float p = 0.f;
#pragma unroll
  for (int j = 0; j < 4; ++j) {
    H2U ua, ur;
    ua.s = xa2[j]; ur.s = xr2[j];
    h2v z = ua.v + ur.v;                              // v_pk_add_f16
    h2v lr = __builtin_elementwise_max(z, z * c02);   // lrelu = max(x, 0.2x)
    p = fdot2f(lr, att2[j], p);
  }
  return p;
}

// ---- prep_w: W[k][c] fp32 -> Wt[c][k] fp16, 6 matrices (one per block) ---
__global__ __launch_bounds__(256) void prep_w(
    const float* __restrict__ W0, const float* __restrict__ W1,
    const float* __restrict__ W2, const float* __restrict__ W3,
    const float* __restrict__ W4, const float* __restrict__ W5,
    __half* __restrict__ Wt) {
  const float* Ws[6] = {W0, W1, W2, W3, W4, W5};
  const float* W = Ws[blockIdx.x];
  __half* o = Wt + (size_t)blockIdx.x * FDIM * FDIM;
  const int t = threadIdx.x;
  const int c4 = (t & 31) * 4;
#pragma unroll
  for (int rep = 0; rep < 16; ++rep) {
    int k = (t >> 5) + rep * 8;
    float4 v = *(const float4*)(W + (size_t)k * FDIM + c4);
    o[(size_t)(c4 + 0) * FDIM + k] = __float2half(v.x);
    o[(size_t)(c4 + 1) * FDIM + k] = __float2half(v.y);
    o[(size_t)(c4 + 2) * FDIM + k] = __float2half(v.z);
    o[(size_t)(c4 + 3) * FDIM + k] = __float2half(v.w);
  }
}

// ---- gemm_mfma: xl = hin@Wl, xr = hin@Wr (fp16 out, fp32 accumulate) ----
// 512 threads = 8 waves: wave w -> output sel=w>>2 (xl/xr), row-block w&3.
template <typename TIN>
__global__ __launch_bounds__(512, 4) void gemm_mfma(
    const TIN* __restrict__ hin, const __half* __restrict__ Wlt,
    const __half* __restrict__ Wrt, __half* __restrict__ xl,
    __half* __restrict__ xr, int n) {
  __shared__ __half Ah[128][40];
  __shared__ __half Bsl[2][128][40];
  const int tid = threadIdx.x;
  const int row0 = blockIdx.x * 128;
  const int wv = tid >> 6;
  const int lane = tid & 63;
  const int sel = wv >> 2;       // 0: xl, 1: xr
  const int rb = wv & 3;         // 32-row block within tile
  const int l15 = lane & 15;
  const int l4 = lane >> 4;      // 0..3

  f32x4 acc[2][8];
#pragma unroll
  for (int i = 0; i < 2; ++i)
#pragma unroll
    for (int j = 0; j < 8; ++j) acc[i][j] = (f32x4){0.f, 0.f, 0.f, 0.f};

  const int sr = tid >> 2;            // A row 0..127
  const int sc = (tid & 3) * 8;       // A k-chunk 0/8/16/24
  const int bslab = tid >> 8;         // 0: Wl, 1: Wr
  const int bidx = tid & 255;
  const int bc = bidx >> 1;           // col 0..127
  const int bko = (bidx & 1) * 16;    // k offset 0/16
  const __half* Wsrc = bslab ? Wrt : Wlt;
  const int gr = row0 + sr;

  for (int k0 = 0; k0 < 128; k0 += 32) {
    if (k0) __syncthreads();
    {  // stage A rows row0+sr, k = k0+sc..+7 -> one 16B LDS write
      union { uint4 u; __half h[8]; } pk;
      if constexpr (sizeof(TIN) == 4) {
        float4 v0 = make_float4(0.f, 0.f, 0.f, 0.f), v1 = v0;
        if (gr < n) {
          v0 = *(const float4*)((const float*)hin + (size_t)gr * FDIM + k0 + sc);
          v1 = *(const float4*)((const float*)hin + (size_t)gr * FDIM + k0 + sc + 4);
        }
        pk.h[0] = __float2half(v0.x); pk.h[1] = __float2half(v0.y);
        pk.h[2] = __float2half(v0.z); pk.h[3] = __float2half(v0.w);
        pk.h[4] = __float2half(v1.x); pk.h[5] = __float2half(v1.y);
        pk.h[6] = __float2half(v1.z); pk.h[7] = __float2half(v1.w);
      } else {
        pk.u = make_uint4(0u, 0u, 0u, 0u);
        if (gr < n)
          pk.u = *(const uint4*)((const __half*)hin + (size_t)gr * FDIM + k0 + sc);
      }
      *(uint4*)&Ah[sr][sc] = pk.u;
    }
    {  // stage B slab: Wt[col][k0+bko .. +16] (already fp16)
      const uint4* src = (const uint4*)(Wsrc + (size_t)bc * FDIM + k0 + bko);
      uint4 w0 = src[0], w1 = src[1];
      *(uint4*)&Bsl[bslab][bc][bko] = w0;
      *(uint4*)&Bsl[bslab][bc][bko + 8] = w1;
    }
    __syncthreads();
    half8 a0 = *(const half8*)&Ah[rb * 32 + l15][l4 * 8];
    half8 a1 = *(const half8*)&Ah[rb * 32 + 16 + l15][l4 * 8];
#pragma unroll
    for (int nf = 0; nf < 8; ++nf) {
      half8 b = *(const half8*)&Bsl[sel][nf * 16 + l15][l4 * 8];
      acc[0][nf] = __builtin_amdgcn_mfma_f32_16x16x32_f16(a0, b, acc[0][nf], 0, 0, 0);
      acc[1][nf] = __builtin_amdgcn_mfma_f32_16x16x32_f16(a1, b, acc[1][nf], 0, 0, 0);
    }
  }

  __half* out = sel ? xr : xl;
#pragma unroll
  for (int af = 0; af < 2; ++af) {
#pragma unroll
    for (int nf = 0; nf < 8; ++nf) {
      int col = nf * 16 + l15;
#pragma unroll
      for (int r = 0; r < 4; ++r) {
        int row = row0 + rb * 32 + af * 16 + l4 * 4 + r;
        if (row < n) out[(size_t)row * FDIM + col] = __float2half(acc[af][nf][r]);
      }
    }
  }
}

// ---------------- CSR build: histogram -> hierarchical scan -> scatter ---
__global__ __launch_bounds__(256) void hist_dst(const int* __restrict__ dstI,
                                                int* __restrict__ deg, int e_cnt) {
  int i = blockIdx.x * blockDim.x + threadIdx.x;
  int stride = gridDim.x * blockDim.x;
  for (; i < e_cnt; i += stride) atomicAdd(&deg[dstI[i]], 1);
}

__global__ __launch_bounds__(1024) void scan_local(
    const int* __restrict__ deg, int* __restrict__ rowptr,
    int* __restrict__ btot, int n) {
  __shared__ int lds[1024];
  const int t = threadIdx.x;
  const int i = blockIdx.x * 1024 + t;
  int v = (i < n) ? deg[i] : 0;
  lds[t] = v;
  __syncthreads();
  for (int off = 1; off < 1024; off <<= 1) {
    int u = (t >= off) ? lds[t - off] : 0;
    __syncthreads();
    lds[t] += u;
    __syncthreads();
  }
  if (i < n) rowptr[i] = lds[t] - v;  // exclusive within block
  if (t == 1023) btot[blockIdx.x] = lds[1023];
}

__global__ __launch_bounds__(1024) void scan_btot(int* __restrict__ btot, int nb) {
  __shared__ int lds[1024];
  const int t = threadIdx.x;
  int v = (t < nb) ? btot[t] : 0;
  lds[t] = v;
  __syncthreads();
  for (int off = 1; off < 1024; off <<= 1) {
    int u = (t >= off) ? lds[t - off] : 0;
    __syncthreads();
    lds[t] += u;
    __syncthreads();
  }
  if (t < nb) btot[t] = lds[t] - v;
}

__global__ __launch_bounds__(1024) void scan_add(
    int* __restrict__ rowptr, int* __restrict__ rowcur,
    const int* __restrict__ btot, int n, int e_cnt) {
  const int i = blockIdx.x * 1024 + threadIdx.x;
  if (i < n) {
    int v = rowptr[i] + btot[blockIdx.x];
    rowptr[i] = v;
    rowcur[i] = v;
  }
  if (i == 0) rowptr[n] = e_cnt;
}

__global__ __launch_bounds__(256) void scatter_csr(
    const int* __restrict__ srcI, const int* __restrict__ dstI,
    int* __restrict__ rowcur, int* __restrict__ csr, int e_cnt) {
  int i = blockIdx.x * blockDim.x + threadIdx.x;
  int stride = gridDim.x * blockDim.x;
  for (; i < e_cnt; i += stride) {
    int pos = atomicAdd(&rowcur[dstI[i]], 1);
    csr[pos] = srcI[i];
  }
}

// ------- fused per-node GATv2: 4 edges/wave, packed fp16, 2-deep prefetch -
// lane = g*16 + q; group g handles edges rs+4t+g; lane q covers features
// q*8..q*8+7 (head = q>>2). Self-loop seeds group 0's state.
template <int LAST>
__global__ __launch_bounds__(256) void fused_attn(
    const __half* __restrict__ xl, const __half* __restrict__ xr,
    const int* __restrict__ rowptr, const int* __restrict__ csr,
    const float* __restrict__ att, const float* __restrict__ bias,
    const float* __restrict__ Wf, const float* __restrict__ bf,
    void* __restrict__ outp, int n) {
  const int nid = (int)((blockIdx.x * (size_t)blockDim.x + threadIdx.x) >> 6);
  const int lane = threadIdx.x & 63;
  if (nid >= n) return;
  const int g = lane >> 4;
  const int q = lane & 15;
  const int f8 = q * 8;
  const h2v c02 = {(_Float16)SLOPE, (_Float16)SLOPE};
  const float4 aA = *(const float4*)(att + f8);
  const float4 aB = *(const float4*)(att + f8 + 4);
  h2v att2[4] = {{(_Float16)aA.x, (_Float16)aA.y}, {(_Float16)aA.z, (_Float16)aA.w},
                 {(_Float16)aB.x, (_Float16)aB.y}, {(_Float16)aB.z, (_Float16)aB.w}};
  U4 xru, xlu;
  xru.u = *(const uint4*)(xr + (size_t)nid * FDIM + f8);
  xlu.u = *(const uint4*)(xl + (size_t)nid * FDIM + f8);

  // self-edge logit
  float ps = edge_logit(xlu.h, xru.h, att2, c02);
  ps += __shfl_xor(ps, 1);
  ps += __shfl_xor(ps, 2);

  float m = (g == 0) ? ps : -1e30f;
  float s = (g == 0) ? 1.f : 0.f;
  float acc[8];
#pragma unroll
  for (int j = 0; j < 4; ++j) {
    float2 f = __half22float2(xlu.h[j]);
    acc[2 * j] = (g == 0) ? f.x : 0.f;
    acc[2 * j + 1] = (g == 0) ? f.y : 0.f;
  }

  const int rs = rowptr[nid], re = rowptr[nid + 1];
  const int j0 = rs + g;
  bool v0 = j0 < re, v1 = (j0 + 4) < re;
  U4 cur, nx1;
  cur.u = make_uint4(0u, 0u, 0u, 0u);
  nx1.u = cur.u;
  if (v0) cur.u = *(const uint4*)(xl + (size_t)csr[j0] * FDIM + f8);
  if (v1) nx1.u = *(const uint4*)(xl + (size_t)csr[j0 + 4] * FDIM + f8);

  for (int t = rs; t < re; t += 4) {
    const int jn = t + 8 + g;
    const bool vn = jn < re;
    U4 nx2;
    nx2.u = make_uint4(0u, 0u, 0u, 0u);
    if (vn) nx2.u = *(const uint4*)(xl + (size_t)csr[jn] * FDIM + f8);

    float p = edge_logit(cur.h, xru.h, att2, c02);
    p += __shfl_xor(p, 1);
    p += __shfl_xor(p, 2);
    if (v0) {
      float mn = fmaxf(m, p);
      float sc = __expf(m - mn);
      float w = __expf(p - mn);
      s = fmaf(s, sc, w);
#pragma unroll
      for (int j = 0; j < 4; ++j) {  // fma_mix: (float)half fused by compiler
        acc[2 * j] = fmaf(acc[2 * j], sc, w * (float)__low2half(cur.h[j]));
        acc[2 * j + 1] = fmaf(acc[2 * j + 1], sc, w * (float)__high2half(cur.h[j]));
      }
      m = mn;
    }
    v0 = v1; v1 = vn; cur = nx1; nx1 = nx2;
  }

  // merge the 4 groups' online-softmax states (xor 16, then xor 32)
#pragma unroll
  for (int off = 16; off <= 32; off <<= 1) {
    float mo = __shfl_xor(m, off);
    float so = __shfl_xor(s, off);
    float ao[8];
#pragma unroll
    for (int j = 0; j < 8; ++j) ao[j] = __shfl_xor(acc[j], off);
    float M = fmaxf(m, mo);
    float e0 = __expf(m - M), e1 = __expf(mo - M);
    s = fmaf(s, e0, so * e1);
#pragma unroll
    for (int j = 0; j < 8; ++j) acc[j] = fmaf(acc[j], e0, ao[j] * e1);
    m = M;
  }

  const float inv = 1.f / s;
  const float4 bA = *(const float4*)(bias + f8);
  const float4 bB = *(const float4*)(bias + f8 + 4);
  const float bb[8] = {bA.x, bA.y, bA.z, bA.w, bB.x, bB.y, bB.z, bB.w};
  float o[8];
#pragma unroll
  for (int j = 0; j < 8; ++j) o[j] = fmaxf(fmaf(acc[j], inv, bb[j]), 0.f);

  if (LAST == 0) {
    if (g == 0) {
      union { uint4 u; __half2 h[4]; } pk;
#pragma unroll
      for (int j = 0; j < 4; ++j) pk.h[j] = __floats2half2_rn(o[2 * j], o[2 * j + 1]);
      *(uint4*)((__half*)outp + (size_t)nid * FDIM + f8) = pk.u;
    }
  } else {
    const float4 wA = *(const float4*)(Wf + f8);
    const float4 wB = *(const float4*)(Wf + f8 + 4);
    float y = fmaf(o[0], wA.x, fmaf(o[1], wA.y, fmaf(o[2], wA.z,
              fmaf(o[3], wA.w, fmaf(o[4], wB.x, fmaf(o[5], wB.y,
              fmaf(o[6], wB.z, o[7] * wB.w)))))));
    y += __shfl_xor(y, 1);
    y += __shfl_xor(y, 2);
    y += __shfl_xor(y, 4);
    y += __shfl_xor(y, 8);
    if (lane == 0) ((float*)outp)[nid] = y + bf[0];
  }
}

extern "C" void kernel_launch(void* const* d_in, const int* in_sizes, int n_in,
                              void* d_out, int out_size, void* d_ws, size_t ws_size,
                              hipStream_t stream) {
  const float* x = (const float*)d_in[0];
  const int* ei = (const int*)d_in[1];
  const int n = in_sizes[0] / FDIM;
  const int e_cnt = in_sizes[1] / 2;
  const int* srcI = ei;
  const int* dstI = ei + e_cnt;

  const float* Wl[3]  = {(const float*)d_in[2], (const float*)d_in[6], (const float*)d_in[10]};
  const float* Wr[3]  = {(const float*)d_in[3], (const float*)d_in[7], (const float*)d_in[11]};
  const float* att[3] = {(const float*)d_in[4], (const float*)d_in[8], (const float*)d_in[12]};
  const float* bs[3]  = {(const float*)d_in[5], (const float*)d_in[9], (const float*)d_in[13]};
  const float* Wf = (const float*)d_in[14];
  const float* bf = (const float*)d_in[15];

  __half* xlh  = (__half*)d_ws;
  __half* xrh  = xlh + (size_t)n * FDIM;
  __half* hbufh = xrh + (size_t)n * FDIM;
  int* deg    = (int*)(hbufh + (size_t)n * FDIM);
  int* rowptr = deg + n;
  int* rowcur = rowptr + n + 1;
  int* csr    = rowcur + n;
  int* btot   = csr + e_cnt;
  __half* Wt  = (__half*)(btot + 1024);   // 6 x 128 x 128 fp16 = 192 KiB

  const int nb = (n + 1023) / 1024;

  // ---- weight transpose/convert + CSR build (serve all 3 layers) ----
  prep_w<<<6, 256, 0, stream>>>(Wl[0], Wr[0], Wl[1], Wr[1], Wl[2], Wr[2], Wt);
  (void)hipMemsetAsync(deg, 0, (size_t)n * sizeof(int), stream);
  hist_dst<<<(e_cnt + 255) / 256, 256, 0, stream>>>(dstI, deg, e_cnt);
  scan_local<<<nb, 1024, 0, stream>>>(deg, rowptr, btot, n);
  scan_btot<<<1, 1024, 0, stream>>>(btot, nb);
  scan_add<<<nb, 1024, 0, stream>>>(rowptr, rowcur, btot, n, e_cnt);
  scatter_csr<<<(e_cnt + 255) / 256, 256, 0, stream>>>(srcI, dstI, rowcur, csr, e_cnt);

  const int gemmGrid = (n + 127) / 128;
  const int nodeBlocks = (n + 3) / 4;  // 4 waves (nodes) per block

  for (int L = 0; L < 3; ++L) {
    const __half* Wlt = Wt + (size_t)(2 * L) * FDIM * FDIM;
    const __half* Wrt = Wt + (size_t)(2 * L + 1) * FDIM * FDIM;
    if (L == 0)
      gemm_mfma<float><<<gemmGrid, 512, 0, stream>>>(x, Wlt, Wrt, xlh, xrh, n);
    else
      gemm_mfma<__half><<<gemmGrid, 512, 0, stream>>>(hbufh, Wlt, Wrt, xlh, xrh, n);
    if (L < 2) {
      fused_attn<0><<<nodeBlocks, 256, 0, stream>>>(xlh, xrh, rowptr, csr, att[L],
                                                    bs[L], nullptr, nullptr, hbufh, n);
    } else {
      fused_attn<1><<<nodeBlocks, 256, 0, stream>>>(xlh, xrh, rowptr, csr, att[L],
                                                    bs[L], Wf, bf, d_out, n);
    }
  }
}